// Round 13
// baseline (16.885 us; speedup 1.0000x reference)
//
#include <hip/hip_runtime.h>

// MLPKANLayer: per-(in,out) scalar MLP 1->2->2->1 (relu), summed over in.
// x:[8192,64] f32 -> out:[8192,64] f32.
//
// R11: kill the weight-preload PREFIX, keep R10's occupancy.
// Evidence: R9 slope -> body ~8.2 us, intercept ~9.6 us; R10 (32 waves/CU)
// only -1.2 us. Diagnosis: r-outer/full-unroll hoists all 26 weight loads
// ahead of row 0, so every wave stalls ~full preload and all 512 blocks
// hit L2 at once (109 MB / 34.5 TB/s ~ 3.2 us of VALU-idle prefix).
// Change: ic-OUTER (rolled, unroll 1) / r-INNER (unrolled) with acc[BT]:
//  - compute starts after ONE i-slice's 6 loads; slices 1..3 stream under
//    the previous slice's 384 VALU cycles (> ~200 cy L2 latency) + 8-wave TLP.
//  - live regs: 13 weight + 16 acc + temps ~ 50 VGPR -> honestly fits the
//    64-reg cap of __launch_bounds__(1024,8); no spill, 32 waves/CU.
//  - weight L2 traffic unchanged (213 KB/block) but now overlapped.
// Unchanged from R10 (one variable per round): scalar-uniform x loads,
// ps 64 KiB unpadded, single barrier, 1-output-per-thread reduce, grid 512.
// Decision: >=15.5 us -> remaining intercept is launch/graph overhead ->
// declare practical roofline.
// (R12 = R11 resubmitted verbatim: bench died on an unresponsive container
// before any measurement.)

#define IN_SIZE  64
#define OUT_SIZE 64
#define BATCH    8192

constexpr int WAVES   = 16;   // waves per block
constexpr int I_CHUNK = 4;    // i's per wave (WAVES * I_CHUNK = 64)
constexpr int BT      = 16;   // batch rows per block (grid = 512 = 2 blocks/CU)

__device__ __forceinline__ void conn(float xv, float2 W1, float2 B1,
                                     float4 W2, float2 B2, float2 W3,
                                     float& s) {
    const float h0 = fmaxf(fmaf(xv, W1.x, B1.x), 0.f);
    const float h1 = fmaxf(fmaf(xv, W1.y, B1.y), 0.f);
    float u0 = fmaf(h1, W2.y, fmaf(h0, W2.x, B2.x));
    float u1 = fmaf(h1, W2.w, fmaf(h0, W2.z, B2.y));
    u0 = fmaxf(u0, 0.f);
    u1 = fmaxf(u1, 0.f);
    s = fmaf(u0, W3.x, s);
    s = fmaf(u1, W3.y, s);
}

__global__ __launch_bounds__(1024, 8) void kan_kernel(
    const float* __restrict__ x,
    const float* __restrict__ w1, const float* __restrict__ b1,
    const float* __restrict__ w2, const float* __restrict__ b2,
    const float* __restrict__ w3, const float* __restrict__ b3,
    float* __restrict__ out)
{
    const int tid   = threadIdx.x;
    const int o     = tid & 63;
    const int wv    = __builtin_amdgcn_readfirstlane(tid >> 6); // provably uniform
    const int brow0 = blockIdx.x * BT;

    __shared__ float ps[WAVES][BT][OUT_SIZE];   // 16*16*64*4 = 64 KiB

    const int i0 = wv * I_CHUNK;

    float acc[BT];
    #pragma unroll
    for (int r = 0; r < BT; ++r) acc[r] = 0.f;
    float bacc = 0.f;   // this wave's share of sum_i b3[i][o]

    // x column base for this wave's i-chunk: x[brow0 + r][i0 + ic], all
    // addresses wave-uniform -> scalar (SMEM) loads, no LDS, no barrier.
    const float* xcol = x + brow0 * IN_SIZE + i0;

    // i-slices OUTER and ROLLED: one slice's 6 loads live at a time
    // (13 VGPRs); next slice's loads stream under this slice's compute.
    #pragma unroll 1
    for (int ic = 0; ic < I_CHUNK; ++ic) {
        const int base = (i0 + ic) * OUT_SIZE + o;
        const float2 W1 = reinterpret_cast<const float2*>(w1)[base];
        const float2 B1 = reinterpret_cast<const float2*>(b1)[base];
        const float4 W2 = reinterpret_cast<const float4*>(w2)[base];
        const float2 B2 = reinterpret_cast<const float2*>(b2)[base];
        const float2 W3 = reinterpret_cast<const float2*>(w3)[base];
        bacc += b3[base];

        #pragma unroll
        for (int r = 0; r < BT; ++r) {
            const float xv = xcol[r * IN_SIZE + ic];  // uniform -> s_load
            conn(xv, W1, B1, W2, B2, W3, acc[r]);
        }
    }

    // Write wave partials (+ this wave's b3 share, matching R10 semantics).
    #pragma unroll
    for (int r = 0; r < BT; ++r) {
        ps[wv][r][o] = acc[r] + bacc * (1.0f / 1.0f);  // bacc added once per wave
    }

    __syncthreads();   // the kernel's only barrier

    // Reduce 16 wave-partials per (r,o): 1024 outputs, 1024 threads -> 1 each.
    // ps[w][r][oo]: w-stride 4 KiB -> bank oo%32, 2 lanes/bank = conflict-free.
    {
        const int r = tid >> 6, oo = tid & 63;
        float v = 0.f;
        #pragma unroll
        for (int w = 0; w < WAVES; ++w) v += ps[w][r][oo];
        out[brow0 * OUT_SIZE + tid] = v;
    }
}

extern "C" void kernel_launch(void* const* d_in, const int* in_sizes, int n_in,
                              void* d_out, int out_size, void* d_ws, size_t ws_size,
                              hipStream_t stream) {
    const float* x  = (const float*)d_in[0];
    const float* w1 = (const float*)d_in[1];
    const float* b1 = (const float*)d_in[2];
    const float* w2 = (const float*)d_in[3];
    const float* b2 = (const float*)d_in[4];
    const float* w3 = (const float*)d_in[5];
    const float* b3 = (const float*)d_in[6];
    float* out = (float*)d_out;

    const int grid = BATCH / BT;   // 512 blocks x 1024 threads = 2 blocks/CU
    kan_kernel<<<grid, 1024, 0, stream>>>(x, w1, b1, w2, b2, w3, b3, out);
}